// Round 4
// baseline (452.778 us; speedup 1.0000x reference)
//
#include <hip/hip_runtime.h>
#include <math.h>

#define L_SEQ 1024
#define DMODEL 512
#define NHEAD 8
#define NB 2

typedef __attribute__((ext_vector_type(8))) short bf8;
typedef __attribute__((ext_vector_type(4))) float f4;

__device__ __forceinline__ short f2bf(float f) {
    unsigned u = __float_as_uint(f);
    unsigned r = u + 0x7FFF + ((u >> 16) & 1);   // RTNE
    return (short)(r >> 16);
}
__device__ __forceinline__ float b2f(short s) {
    return __uint_as_float(((unsigned)(unsigned short)s) << 16);
}

// ---------------------------------------------------------------------------
// q/k/v fp32 [2048][512] -> A-type fragment order bf16:
// frag f = mb*16+kb (mb=row/16, kb=k/32), element (m=mb*16+lr, k=kb*32+lq*8+j)
// stored at [f*64 + lane]*8 + j.  One wave handles one frag.
// ---------------------------------------------------------------------------
__global__ __launch_bounds__(256) void cast_afrag_kernel(
    const float* __restrict__ q, const float* __restrict__ k,
    const float* __restrict__ v,
    short* __restrict__ qb, short* __restrict__ kb2, short* __restrict__ vb)
{
    const float* src = (blockIdx.y == 0) ? q : (blockIdx.y == 1) ? k : v;
    short* dst = (blockIdx.y == 0) ? qb : (blockIdx.y == 1) ? kb2 : vb;
    const int tid = blockIdx.x * 256 + threadIdx.x;   // 131072 threads
    const int f = tid >> 6, lane = tid & 63;
    const int mb = f >> 4, kbl = f & 15;
    const int lr = lane & 15, lq = lane >> 4;
    const float* s = src + (size_t)(mb * 16 + lr) * 512 + kbl * 32 + lq * 8;
    float4 a = *(const float4*)s;
    float4 b = *(const float4*)(s + 4);
    bf8 o;
    o[0] = f2bf(a.x); o[1] = f2bf(a.y); o[2] = f2bf(a.z); o[3] = f2bf(a.w);
    o[4] = f2bf(b.x); o[5] = f2bf(b.y); o[6] = f2bf(b.z); o[7] = f2bf(b.w);
    *(bf8*)(dst + (size_t)tid * 8) = o;
}

// ---------------------------------------------------------------------------
// W fp32 [512k][512n] -> B-type fragment order bf16:
// frag f = nb*16+kb, element (n=nb*16+lr, k=kb*32+lq*8+j) at [f*64+lane]*8+j
// ---------------------------------------------------------------------------
__global__ __launch_bounds__(256) void wfrag_kernel(
    const float* __restrict__ s0, const float* __restrict__ s1,
    const float* __restrict__ s2, const float* __restrict__ s3,
    short* __restrict__ d0, short* __restrict__ d1,
    short* __restrict__ d2, short* __restrict__ d3)
{
    const float* src; short* dst;
    switch (blockIdx.y) {
        case 0: src = s0; dst = d0; break;
        case 1: src = s1; dst = d1; break;
        case 2: src = s2; dst = d2; break;
        default: src = s3; dst = d3; break;
    }
    const int tid = blockIdx.x * 256 + threadIdx.x;   // 32768 threads
    const int f = tid >> 6, lane = tid & 63;
    const int nb = f >> 4, kbl = f & 15;
    const int lr = lane & 15, lq = lane >> 4;
    const int n = nb * 16 + lr, kb0 = kbl * 32 + lq * 8;
    bf8 o;
#pragma unroll
    for (int j = 0; j < 8; ++j) o[j] = f2bf(src[(size_t)(kb0 + j) * 512 + n]);
    *(bf8*)(dst + (size_t)tid * 8) = o;
}

// ---------------------------------------------------------------------------
// QKV projection GEMM on fragment-ordered operands.
// Block: 64m x 64n; wave w owns m-frag mb = by*4+w, 4 n-frags. K=512.
// Outputs written directly in the fragment layouts the attention kernel needs:
//   z=0 qh, z=1 kh:  [b][h][lb(64)][kd(2)][lane][8]   (A/B-type over d)
//   z=2 vht:         [b][h][db(4)][kl(32)][lane][8]   (B-type: n=d, k=l)
// ---------------------------------------------------------------------------
__global__ __launch_bounds__(256) void qkv_proj_kernel(
    const short* __restrict__ qb, const short* __restrict__ kb2,
    const short* __restrict__ vb,
    const short* __restrict__ Wq, const short* __restrict__ Wk,
    const short* __restrict__ Wv,
    const float* __restrict__ b_q, const float* __restrict__ b_k,
    const float* __restrict__ b_v,
    short* __restrict__ qh, short* __restrict__ kh, short* __restrict__ vht)
{
    const int z = blockIdx.z;
    const short* A  = (z == 0) ? qb : (z == 1) ? kb2 : vb;
    const short* Bf = (z == 0) ? Wq : (z == 1) ? Wk : Wv;
    const float* bias = (z == 0) ? b_q : (z == 1) ? b_k : b_v;

    const int w = threadIdx.x >> 6, lane = threadIdx.x & 63;
    const int lr = lane & 15, lq = lane >> 4;
    const int mb = blockIdx.y * 4 + w;
    const int nb0 = blockIdx.x * 4;

    f4 acc[4];
    const f4 zero = {0.f, 0.f, 0.f, 0.f};
#pragma unroll
    for (int nf = 0; nf < 4; ++nf) acc[nf] = zero;

    for (int kbl = 0; kbl < 16; ++kbl) {
        bf8 a = *(const bf8*)(A + ((size_t)(mb * 16 + kbl) * 64 + lane) * 8);
#pragma unroll
        for (int nf = 0; nf < 4; ++nf) {
            bf8 b = *(const bf8*)(Bf + ((size_t)((nb0 + nf) * 16 + kbl) * 64 + lane) * 8);
            acc[nf] = __builtin_amdgcn_mfma_f32_16x16x32_bf16(a, b, acc[nf], 0, 0, 0);
        }
    }

#pragma unroll
    for (int nf = 0; nf < 4; ++nf) {
        const int n = (nb0 + nf) * 16 + lr;
        const float bv = bias[n];
        const int h = n >> 6, d = n & 63;
#pragma unroll
        for (int r = 0; r < 4; ++r) {
            const int m = mb * 16 + lq * 4 + r;
            const short val = f2bf(acc[nf][r] + bv);
            const int bi = m >> 10, l = m & 1023;
            if (z < 2) {
                const int lb = l >> 4, lrr = l & 15;
                const int kd = d >> 5, lqq = (d >> 3) & 3, j = d & 7;
                short* dst = (z == 0) ? qh : kh;
                dst[((((size_t)bi * 8 + h) * 64 + lb) * 2 + kd) * 512
                    + (lqq * 16 + lrr) * 8 + j] = val;
            } else {
                const int db = d >> 4, lrr = d & 15;
                const int kl = l >> 5, lqq = (l >> 3) & 3, j = l & 7;
                vht[((((size_t)bi * 8 + h) * 4 + db) * 32 + kl) * 512
                    + (lqq * 16 + lrr) * 8 + j] = val;
            }
        }
    }
}

// ---------------------------------------------------------------------------
// fc GEMM: A = pv frags [mb(128)][kb(16)][lane][8], B = Wfc frags, out fp32.
// ---------------------------------------------------------------------------
__global__ __launch_bounds__(256) void fc_kernel(
    const short* __restrict__ A, const short* __restrict__ Bf,
    const float* __restrict__ bias, float* __restrict__ C)
{
    const int w = threadIdx.x >> 6, lane = threadIdx.x & 63;
    const int lr = lane & 15, lq = lane >> 4;
    const int mb = blockIdx.y * 4 + w;
    const int nb0 = blockIdx.x * 4;

    f4 acc[4];
    const f4 zero = {0.f, 0.f, 0.f, 0.f};
#pragma unroll
    for (int nf = 0; nf < 4; ++nf) acc[nf] = zero;

    for (int kbl = 0; kbl < 16; ++kbl) {
        bf8 a = *(const bf8*)(A + ((size_t)(mb * 16 + kbl) * 64 + lane) * 8);
#pragma unroll
        for (int nf = 0; nf < 4; ++nf) {
            bf8 b = *(const bf8*)(Bf + ((size_t)((nb0 + nf) * 16 + kbl) * 64 + lane) * 8);
            acc[nf] = __builtin_amdgcn_mfma_f32_16x16x32_bf16(a, b, acc[nf], 0, 0, 0);
        }
    }
#pragma unroll
    for (int nf = 0; nf < 4; ++nf) {
        const int n = nb0 * 16 + nf * 16 + lr;
        const float bv = bias[n];
#pragma unroll
        for (int r = 0; r < 4; ++r)
            C[(size_t)(mb * 16 + lq * 4 + r) * 512 + n] = acc[nf][r] + bv;
    }
}

// ---------------------------------------------------------------------------
// Fused attention v2. Grid (hg=4, ltile=64, b=2) = 512 blocks, 256 thr.
// Per block: head pair, 16 q-rows, all 1024 keys.
// pack(coalesced) -> per head: per 256-col strip [QK-MFMA -> Sstrip -> bias
// (linear, packed regs) -> bf16 Sb] -> 2-pass softmax (row-owned, no extra
// syncs) -> coalesced attn write + LDS-fragment MFMA PV.
// ---------------------------------------------------------------------------
#define SBS 1040   // Sb row stride (shorts): 2080B rows, 16B aligned, uniform banks
#define SSS 260    // Sstrip row stride (floats)

__global__ __launch_bounds__(256, 3) void attn_fused2_kernel(
    const short* __restrict__ qh, const short* __restrict__ kh,
    const short* __restrict__ vht,
    const int* __restrict__ mask,
    const int* __restrict__ tf1, const int* __restrict__ tf2,
    const int* __restrict__ tf3, const int* __restrict__ tf4,
    const int* __restrict__ tf5,
    const float* __restrict__ emb1, const float* __restrict__ emb2,
    const float* __restrict__ emb3, const float* __restrict__ emb4,
    const float* __restrict__ emb5,
    float* __restrict__ attn, short* __restrict__ pv)
{
    const int hg = blockIdx.x, lt = blockIdx.y, b = blockIdx.z;
    const int l0 = lt * 16;
    const int t = threadIdx.x, w = t >> 6, lane = t & 63;
    const int lr = lane & 15, lq = lane >> 4;
    const int prow = t >> 4;            // pack/bias row owned by this thread
    const int pcol = (t & 15) * 16;     // strip-local col base

    __shared__ short Sb[16 * SBS];      // 33.3 KB bf16 score/prob tile
    __shared__ float Sstrip[16 * SSS];  // 16.6 KB fp32 raw-score strip
    __shared__ float embA[5 * 64];      // per-head emb slice
    __shared__ float red[16 * 17];
    __shared__ float rinvb[16];

    // ---- pack tf+mask (coalesced int4 loads), 64 positions/thread ----
    uint4 pk[16];
    {
        const size_t rb = ((size_t)(b * L_SEQ + l0 + prow)) * L_SEQ;
#pragma unroll
        for (int st = 0; st < 4; ++st)
#pragma unroll
            for (int c = 0; c < 4; ++c) {
                const size_t off = rb + st * 256 + pcol + c * 4;
                int4 mm = *(const int4*)(mask + off);
                int4 a1 = *(const int4*)(tf1 + off);
                int4 a2 = *(const int4*)(tf2 + off);
                int4 a3 = *(const int4*)(tf3 + off);
                int4 a4 = *(const int4*)(tf4 + off);
                int4 a5 = *(const int4*)(tf5 + off);
                uint4 p;
                p.x = (mm.x ? 0x80000000u : 0u) | (a1.x >= 0 ? (0x40000000u | (unsigned)a1.x) : 0u)
                    | ((unsigned)a2.x << 6) | ((unsigned)a3.x << 12)
                    | ((unsigned)a4.x << 18) | ((unsigned)a5.x << 24);
                p.y = (mm.y ? 0x80000000u : 0u) | (a1.y >= 0 ? (0x40000000u | (unsigned)a1.y) : 0u)
                    | ((unsigned)a2.y << 6) | ((unsigned)a3.y << 12)
                    | ((unsigned)a4.y << 18) | ((unsigned)a5.y << 24);
                p.z = (mm.z ? 0x80000000u : 0u) | (a1.z >= 0 ? (0x40000000u | (unsigned)a1.z) : 0u)
                    | ((unsigned)a2.z << 6) | ((unsigned)a3.z << 12)
                    | ((unsigned)a4.z << 18) | ((unsigned)a5.z << 24);
                p.w = (mm.w ? 0x80000000u : 0u) | (a1.w >= 0 ? (0x40000000u | (unsigned)a1.w) : 0u)
                    | ((unsigned)a2.w << 6) | ((unsigned)a3.w << 12)
                    | ((unsigned)a4.w << 18) | ((unsigned)a5.w << 24);
                pk[st * 4 + c] = p;
            }
    }

    const f4 zero = {0.f, 0.f, 0.f, 0.f};

    for (int hh = 0; hh < 2; ++hh) {
        const int h = hg * 2 + hh;
        __syncthreads();   // Sb / embA free from previous head

        // per-head emb slice
        for (int i = t; i < 320; i += 256) {
            const int j = i >> 6, idx = i & 63;
            const float* ep = (j == 0) ? emb1 : (j == 1) ? emb2 : (j == 2) ? emb3
                            : (j == 3) ? emb4 : emb5;
            embA[i] = ep[idx * NHEAD + h];
        }

        // Q fragments for this head (16 rows x 64 d)
        const short* qf = qh + (((size_t)(b * 8 + h) * 64 + lt) * 2) * 512;
        bf8 aq0 = *(const bf8*)(qf + lane * 8);
        bf8 aq1 = *(const bf8*)(qf + 512 + lane * 8);

        float runmax = -INFINITY;

        for (int st = 0; st < 4; ++st) {
            // ---- QK^T: wave w -> strip cols [w*64, w*64+64) ----
            f4 acc[4];
#pragma unroll
            for (int nf = 0; nf < 4; ++nf) acc[nf] = zero;
            const short* kf = kh + ((size_t)(b * 8 + h) * 64) * 1024;
#pragma unroll
            for (int nf = 0; nf < 4; ++nf) {
                const int lb = st * 16 + w * 4 + nf;
                bf8 b0 = *(const bf8*)(kf + (size_t)lb * 1024 + lane * 8);
                bf8 b1 = *(const bf8*)(kf + (size_t)lb * 1024 + 512 + lane * 8);
                acc[nf] = __builtin_amdgcn_mfma_f32_16x16x32_bf16(aq0, b0, acc[nf], 0, 0, 0);
                acc[nf] = __builtin_amdgcn_mfma_f32_16x16x32_bf16(aq1, b1, acc[nf], 0, 0, 0);
            }
            __syncthreads();   // Sstrip free (prev bias done; st=0: embA stores done)
#pragma unroll
            for (int nf = 0; nf < 4; ++nf)
#pragma unroll
                for (int r = 0; r < 4; ++r)
                    Sstrip[(lq * 4 + r) * SSS + w * 64 + nf * 16 + lr] = acc[nf][r];
            __syncthreads();

            // ---- bias/mask/scale (linear, packed regs) -> bf16 Sb ----
#pragma unroll
            for (int c = 0; c < 4; ++c) {
                float4 s4 = *(const float4*)&Sstrip[prow * SSS + pcol + c * 4];
                const uint4 P = pk[st * 4 + c];
                float vv[4];
                const unsigned pks[4] = {P.x, P.y, P.z, P.w};
                const float sv[4] = {s4.x, s4.y, s4.z, s4.w};
#pragma unroll
                for (int e = 0; e < 4; ++e) {
                    const unsigned p = pks[e];
                    float bvv = 0.f;
                    if (p & 0x40000000u)
                        bvv = embA[p & 63] + embA[64 + ((p >> 6) & 63)]
                            + embA[128 + ((p >> 12) & 63)] + embA[192 + ((p >> 18) & 63)]
                            + embA[256 + ((p >> 24) & 63)];
                    float val = (sv[e] + bvv) * 0.125f;
                    if (p & 0x80000000u) val = -INFINITY;
                    vv[e] = val;
                    runmax = fmaxf(runmax, val);
                }
                short4 o;
                o.x = f2bf(vv[0]); o.y = f2bf(vv[1]); o.z = f2bf(vv[2]); o.w = f2bf(vv[3]);
                *(short4*)&Sb[prow * SBS + st * 256 + pcol + c * 4] = o;
            }
        }

        // ---- row max ----
        red[prow * 17 + (t & 15)] = runmax;
        __syncthreads();
        float M = -INFINITY;
#pragma unroll
        for (int i = 0; i < 16; ++i) M = fmaxf(M, red[prow * 17 + i]);

        // ---- exp + partial sums (thread-owned cells, in-place) ----
        float sum = 0.f;
#pragma unroll
        for (int st = 0; st < 4; ++st)
#pragma unroll
            for (int c = 0; c < 4; ++c) {
                short4* sp = (short4*)&Sb[prow * SBS + st * 256 + pcol + c * 4];
                short4 s4 = *sp;
                float e0 = __expf(b2f(s4.x) - M);
                float e1 = __expf(b2f(s4.y) - M);
                float e2 = __expf(b2f(s4.z) - M);
                float e3 = __expf(b2f(s4.w) - M);
                sum += e0 + e1 + e2 + e3;
                short4 o;
                o.x = f2bf(e0); o.y = f2bf(e1); o.z = f2bf(e2); o.w = f2bf(e3);
                *sp = o;
            }
        __syncthreads();   // everyone done reading red (max) before sum overwrite
        red[prow * 17 + (t & 15)] = sum;
        __syncthreads();
        if (t < 16) {
            float tot = 0.f;
#pragma unroll
            for (int i = 0; i < 16; ++i) tot += red[t * 17 + i];
            rinvb[t] = 1.0f / tot;
        }
        __syncthreads();

        // ---- normalized attn write (coalesced float4) ----
        float* ab = attn + (((size_t)(h * NB + b)) * L_SEQ + l0) * L_SEQ;
#pragma unroll
        for (int i = 0; i < 16; ++i) {
            const float ri = rinvb[i];
            short4 s4 = *(const short4*)&Sb[i * SBS + 4 * t];
            float4 o;
            o.x = b2f(s4.x) * ri; o.y = b2f(s4.y) * ri;
            o.z = b2f(s4.z) * ri; o.w = b2f(s4.w) * ri;
            *(float4*)&ab[(size_t)i * L_SEQ + 4 * t] = o;
        }

        // ---- PV: wave w -> d-cols [w*16, w*16+16), K = 1024 from Sb ----
        f4 pa = zero, pb = zero;
        const short* vf = vht + (((size_t)(b * 8 + h) * 4 + w) * 32) * 512;
        for (int kl = 0; kl < 32; kl += 2) {
            bf8 a0 = *(const bf8*)&Sb[lr * SBS + kl * 32 + lq * 8];
            bf8 v0 = *(const bf8*)(vf + (size_t)kl * 512 + lane * 8);
            pa = __builtin_amdgcn_mfma_f32_16x16x32_bf16(a0, v0, pa, 0, 0, 0);
            bf8 a1 = *(const bf8*)&Sb[lr * SBS + (kl + 1) * 32 + lq * 8];
            bf8 v1 = *(const bf8*)(vf + (size_t)(kl + 1) * 512 + lane * 8);
            pb = __builtin_amdgcn_mfma_f32_16x16x32_bf16(a1, v1, pb, 0, 0, 0);
        }
#pragma unroll
        for (int r = 0; r < 4; ++r) {
            const int row = lq * 4 + r;
            const float val = (pa[r] + pb[r]) * rinvb[row];
            // pv A-frag store for fc: m = b*1024+l0+row, k = h*64+w*16+lr
            const int mb = b * 64 + lt;
            const int kb = h * 2 + (w >> 1);
            const int lq2 = (w & 1) * 2 + (lr >> 3), j = lr & 7;
            pv[((size_t)(mb * 16 + kb) * 64 + lq2 * 16 + row) * 8 + j] = f2bf(val);
        }
    }
}

// ---------------------------------------------------------------------------
// residual add + LayerNorm
// ---------------------------------------------------------------------------
__global__ __launch_bounds__(256) void ln_kernel(
    const float* __restrict__ x, const float* __restrict__ res,
    const float* __restrict__ g, const float* __restrict__ bvec,
    float* __restrict__ out)
{
    const int row = blockIdx.x;
    const int t = threadIdx.x;
    float2 xv = ((const float2*)(x + (size_t)row * DMODEL))[t];
    float2 rv = ((const float2*)(res + (size_t)row * DMODEL))[t];
    const float a = xv.x + rv.x;
    const float c = xv.y + rv.y;
    float s = a + c, sq = a * a + c * c;
#pragma unroll
    for (int off = 32; off; off >>= 1) {
        s  += __shfl_down(s, off);
        sq += __shfl_down(sq, off);
    }
    __shared__ float ssum[4], ssq[4];
    __shared__ float smu, srs;
    const int wid = t >> 6, lane = t & 63;
    if (lane == 0) { ssum[wid] = s; ssq[wid] = sq; }
    __syncthreads();
    if (t == 0) {
        float ts = ssum[0] + ssum[1] + ssum[2] + ssum[3];
        float tq = ssq[0] + ssq[1] + ssq[2] + ssq[3];
        float mu = ts * (1.0f / DMODEL);
        float var = tq * (1.0f / DMODEL) - mu * mu;
        smu = mu;
        srs = rsqrtf(var + 1e-5f);
    }
    __syncthreads();
    const float mu = smu, rs = srs;
    float2 gv = ((const float2*)g)[t];
    float2 bv = ((const float2*)bvec)[t];
    float2 o;
    o.x = (a - mu) * rs * gv.x + bv.x;
    o.y = (c - mu) * rs * gv.y + bv.y;
    ((float2*)(out + (size_t)row * DMODEL))[t] = o;
}

extern "C" void kernel_launch(void* const* d_in, const int* in_sizes, int n_in,
                              void* d_out, int out_size, void* d_ws, size_t ws_size,
                              hipStream_t stream)
{
    const float* q    = (const float*)d_in[0];
    const float* k    = (const float*)d_in[1];
    const float* v    = (const float*)d_in[2];
    const int*   mask = (const int*)d_in[3];
    const int*   tf1  = (const int*)d_in[4];
    const int*   tf2  = (const int*)d_in[5];
    const int*   tf3  = (const int*)d_in[6];
    const int*   tf4  = (const int*)d_in[7];
    const int*   tf5  = (const int*)d_in[8];
    const float* w_q  = (const float*)d_in[9];
    const float* b_q  = (const float*)d_in[10];
    const float* w_k  = (const float*)d_in[11];
    const float* b_k  = (const float*)d_in[12];
    const float* w_v  = (const float*)d_in[13];
    const float* b_v  = (const float*)d_in[14];
    const float* emb1 = (const float*)d_in[15];
    const float* emb2 = (const float*)d_in[16];
    const float* emb3 = (const float*)d_in[17];
    const float* emb4 = (const float*)d_in[18];
    const float* emb5 = (const float*)d_in[19];
    const float* fc_w = (const float*)d_in[20];
    const float* fc_b = (const float*)d_in[21];
    const float* ln_g = (const float*)d_in[22];
    const float* ln_b = (const float*)d_in[23];

    float* out  = (float*)d_out;                       // [2048][512]
    float* attn = out + (size_t)NB * L_SEQ * DMODEL;   // [16][1024][1024]

    char* wsb = (char*)d_ws;
    short* qb   = (short*)(wsb + 0);                    // 2 MiB A-frags
    short* kb2  = (short*)(wsb + (2u << 20));
    short* vb   = (short*)(wsb + (4u << 20));
    short* Wq   = (short*)(wsb + (6u << 20));           // 0.5 MiB B-frags each
    short* Wk   = (short*)(wsb + (6u << 20) + (512u << 10));
    short* Wv   = (short*)(wsb + (7u << 20));
    short* Wfc  = (short*)(wsb + (7u << 20) + (512u << 10));
    short* qh   = (short*)(wsb + (8u << 20));           // 2 MiB [b][h][lb][kd] frags
    short* kh   = (short*)(wsb + (10u << 20));          // 2 MiB
    short* vht  = (short*)(wsb + (12u << 20));          // 2 MiB [b][h][db][kl] frags
    short* pv   = (short*)(wsb + (14u << 20));          // 2 MiB A-frags for fc
    float* fco  = (float*)(wsb + (16u << 20));          // 4 MiB fp32

    cast_afrag_kernel<<<dim3(512, 3), 256, 0, stream>>>(q, k, v, qb, kb2, vb);
    wfrag_kernel<<<dim3(128, 4), 256, 0, stream>>>(
        w_q, w_k, w_v, fc_w, Wq, Wk, Wv, Wfc);

    qkv_proj_kernel<<<dim3(8, 32, 3), 256, 0, stream>>>(
        qb, kb2, vb, Wq, Wk, Wv, b_q, b_k, b_v, qh, kh, vht);

    attn_fused2_kernel<<<dim3(4, 64, 2), 256, 0, stream>>>(
        qh, kh, vht, mask, tf1, tf2, tf3, tf4, tf5,
        emb1, emb2, emb3, emb4, emb5, attn, pv);

    fc_kernel<<<dim3(8, 32), 256, 0, stream>>>(pv, Wfc, fc_b, fco);

    ln_kernel<<<NB * L_SEQ, 256, 0, stream>>>(fco, q, ln_g, ln_b, out);
}